// Round 1
// baseline (268.199 us; speedup 1.0000x reference)
//
#include <hip/hip_runtime.h>
#include <stdint.h>

// triplet_loss_cl: loss = mean_i(-log(softmax(q G^T)[i,i] + 1e-5)), N=8192, D=256.
// Flash-style, never materialize logits. q pre-scaled by log2(e); MFMA C-input
// initialized to -KOFF so logits exit MFMA already offset; epilogue is bare exp2.
// Offset cancels exactly in p = exp2(l_ii)/sum exp2(l).
//
// Round 7: MX-scaled fp8 MFMA (mfma_scale_f32_16x16x128_f8f6f4, unit e8m0 scales
// = exact fp8 math) -> 2x the matrix rate of non-scaled fp8 (4661 vs 2047 TF,
// m21/m148). Panel repacked so each lane's 32 contiguous-k bytes are two linear
// 16B slots: tile(kb,cf) = 2KB laid out [h][lane][16B]; A global reads and B LDS
// reads are 2x dwordx4/b128 at lane*16 (+1024) -- coalesced, conflict-free.
// A/B use the identical packing, so any k-permutation in the HW fragment map
// applies to both operands and cancels in the dot product.

#define LOG2E 1.44269504f
#define KOFF  92.3324826f          // 64 * log2(e); cancels exactly in p = e_ii/Z

typedef __attribute__((ext_vector_type(4))) float f32x4;
typedef __attribute__((ext_vector_type(4))) int   i32x4;
typedef __attribute__((ext_vector_type(8))) int   i32x8;

typedef __attribute__((address_space(1))) const uint32_t gu32;
typedef __attribute__((address_space(3))) uint32_t lu32;

static __device__ __forceinline__ i32x8 cat8(i32x4 lo, i32x4 hi) {
    i32x8 r;
    r[0] = lo[0]; r[1] = lo[1]; r[2] = lo[2]; r[3] = lo[3];
    r[4] = hi[0]; r[5] = hi[1]; r[6] = hi[2]; r[7] = hi[3];
    return r;
}

// ---- kernel 0: fp32 row-major [8192][256] -> fp8 e4m3 K=128 fragment layout ----
// Panel = 64 rows x 256 k = 16 KB, split into 8 tiles (kb in 2, cf in 4) of 2 KB.
// Tile holds rows cf*16+l15, k = kb*128 + quad*32 .. +32 per lane (l=quad*16+l15),
// stored as [h in 2][lane][16B] so fragment loads are linear b128 pairs.
// Thread o -> row = o>>5 (coalesced reads), slot = o&31 (8 k-values each).
__global__ __launch_bounds__(256) void k_cvt(const float* __restrict__ q,
                                             const float* __restrict__ g,
                                             char* __restrict__ qb,
                                             char* __restrict__ gb) {
    int o = blockIdx.x * 256 + threadIdx.x;        // grid 2048: q then g
    const float* src = q;
    char* dst = qb;
    float sc = LOG2E;
    if (o >= 262144) { o -= 262144; src = g; dst = gb; sc = 1.0f; }
    int row = o >> 5, slot = o & 31;
    const float4* sp = (const float4*)(src + row * 256 + slot * 8);
    float4 a = sp[0], b = sp[1];
    uint32_t w0 = __builtin_amdgcn_cvt_pk_fp8_f32(a.x * sc, a.y * sc, 0, false);
    w0 = __builtin_amdgcn_cvt_pk_fp8_f32(a.z * sc, a.w * sc, w0, true);
    uint32_t w1 = __builtin_amdgcn_cvt_pk_fp8_f32(b.x * sc, b.y * sc, 0, false);
    w1 = __builtin_amdgcn_cvt_pk_fp8_f32(b.z * sc, b.w * sc, w1, true);
    int p = row >> 6, cf = (row >> 4) & 3, l15 = row & 15;
    int kb = slot >> 4;                            // which 128-k block
    int gi = slot & 15;                            // 8-byte granule within block
    int quad = gi >> 2;                            // lane quad (k = quad*32..+32)
    int j = gi & 3;                                // byte granule within lane's 32B
    uint2 wv; wv.x = w0; wv.y = w1;
    *(uint2*)(dst + (size_t)p * 16384 + ((kb * 4 + cf) << 11)
              + ((j >> 1) << 10) + (quad * 16 + l15) * 16 + (j & 1) * 8) = wv;
}

// ---- kernel 1: per-row Z partials (+ diagonal offset-logits) ----
// grid 1024 = 32 row-tiles (BM=256) x 32 col-splits (256 cols). 4 waves x 64 rows.
// Per jt (64-col tile): DMA 16 KB to LDS, 4 cf x (4 ds_read_b128 + 8 MX-MFMA),
// exp2 epilogue. Unit scales (e8m0 0x7F = 2^0) keep the math exact fp8.
__global__ __launch_bounds__(256, 2) void k_main(const char* __restrict__ qb,
                                                 const char* __restrict__ gb,
                                                 float* __restrict__ zpart,
                                                 float* __restrict__ diag) {
    __shared__ char lds[16384];                    // one 64-col fp8 B tile
    const int tid  = threadIdx.x;
    const int wave = tid >> 6;
    const int lane = tid & 63;
    const int l15  = lane & 15;
    const int quad = lane >> 4;
    const int t    = blockIdx.x >> 5;              // row-tile (256 rows)
    const int cs   = blockIdx.x & 31;              // col-split (256 cols)
    const int rowbase = t * 256 + wave * 64;

    // A fragments: wave owns exactly q-panel (t*4+wave); rowgroup rg = tile cf.
    i32x8 afrag[4][2];                             // 64 VGPRs
    {
        const char* qp = qb + (size_t)(t * 4 + wave) * 16384 + lane * 16;
#pragma unroll
        for (int rg = 0; rg < 4; ++rg)
#pragma unroll
            for (int kb = 0; kb < 2; ++kb) {
                const char* tp = qp + ((kb * 4 + rg) << 11);
                afrag[rg][kb] = cat8(*(const i32x4*)tp, *(const i32x4*)(tp + 1024));
            }
    }

    float zacc[4][4];
#pragma unroll
    for (int rg = 0; rg < 4; ++rg)
#pragma unroll
        for (int r = 0; r < 4; ++r) zacc[rg][r] = 0.f;

    const bool bd = (t == cs);                     // square block on the diagonal

    for (int jt = 0; jt < 4; ++jt) {
        const char* gp = gb + (size_t)(cs * 4 + jt) * 16384;
        // stage 16 KB: 4 waves x 4 x 1KB DMA (linear; dest = uniform + lane*16)
#pragma unroll
        for (int i = 0; i < 4; ++i) {
            int c = wave * 4 + i;
            __builtin_amdgcn_global_load_lds(
                (gu32*)(gp + (c << 10) + (lane << 4)),
                (lu32*)(lds + (c << 10)), 16, 0, 0);
        }
        __syncthreads();

        const bool dg = bd && (jt == wave);        // this tile holds our diagonal
#pragma unroll
        for (int cf = 0; cf < 4; ++cf) {
            f32x4 acc[4];
#pragma unroll
            for (int rg = 0; rg < 4; ++rg)
                acc[rg] = (f32x4){-KOFF, -KOFF, -KOFF, -KOFF};
#pragma unroll
            for (int kb = 0; kb < 2; ++kb) {
                const char* bp = lds + ((kb * 4 + cf) << 11) + lane * 16;
                i32x8 b = cat8(*(const i32x4*)bp, *(const i32x4*)(bp + 1024));
#pragma unroll
                for (int rg = 0; rg < 4; ++rg)
                    acc[rg] = __builtin_amdgcn_mfma_scale_f32_16x16x128_f8f6f4(
                        afrag[rg][kb], b, acc[rg],
                        0, 0,                       // cbsz/blgp: fp8 e4m3 / fp8 e4m3
                        0, 0x7f7f7f7f,              // scale A: e8m0 127 -> x1
                        0, 0x7f7f7f7f);             // scale B: e8m0 127 -> x1
            }
            // C/D layout: col=lane&15, row=quad*4+reg (shape-determined, m127/m128)
#pragma unroll
            for (int rg = 0; rg < 4; ++rg)
#pragma unroll
                for (int r = 0; r < 4; ++r)
                    zacc[rg][r] += __builtin_amdgcn_exp2f(acc[rg][r]);
            if (dg) {                              // diag: rg==cf, col l15 == row quad*4+r
#pragma unroll
                for (int r = 0; r < 4; ++r)
                    if (quad * 4 + r == l15)
                        diag[rowbase + cf * 16 + l15] = acc[cf][r];
            }
        }
        __syncthreads();
    }

    // fold the 16 column-lane-classes (lanes differing in bits 0..3 share a row)
#pragma unroll
    for (int d = 1; d < 16; d <<= 1)
#pragma unroll
        for (int rg = 0; rg < 4; ++rg)
#pragma unroll
            for (int r = 0; r < 4; ++r)
                zacc[rg][r] += __shfl_xor(zacc[rg][r], d, 64);

    if (l15 == 0) {
#pragma unroll
        for (int rg = 0; rg < 4; ++rg)
#pragma unroll
            for (int r = 0; r < 4; ++r)
                zpart[(rowbase + rg * 16 + quad * 4 + r) * 32 + cs] = zacc[rg][r];
    }
}

// ---- kernel 2a: per-row loss, 32-block tree ----
__global__ __launch_bounds__(256) void k_fin1(const float* __restrict__ zpart,
                                              const float* __restrict__ diag,
                                              float* __restrict__ partial) {
    __shared__ float red[4];
    int r = blockIdx.x * 256 + threadIdx.x;
    const float4* z = (const float4*)(zpart + r * 32);
    float Z = 0.f;
#pragma unroll
    for (int i = 0; i < 8; ++i) {
        float4 a = z[i];
        Z += (a.x + a.y) + (a.z + a.w);
    }
    float p = __builtin_amdgcn_exp2f(diag[r]) / Z;  // diag already has -KOFF folded
    float v = -logf(p + 1e-5f);
#pragma unroll
    for (int dd = 1; dd < 64; dd <<= 1) v += __shfl_xor(v, dd, 64);
    if ((threadIdx.x & 63) == 0) red[threadIdx.x >> 6] = v;
    __syncthreads();
    if (threadIdx.x == 0)
        partial[blockIdx.x] = (red[0] + red[1]) + (red[2] + red[3]);
}

// ---- kernel 2b: final reduce ----
__global__ void k_fin2(const float* __restrict__ partial, float* __restrict__ out) {
    float v = (threadIdx.x < 32) ? partial[threadIdx.x] : 0.f;
#pragma unroll
    for (int d = 1; d < 32; d <<= 1) v += __shfl_xor(v, d, 64);
    if (threadIdx.x == 0) out[0] = v * (1.f / 8192.f);
}

extern "C" void kernel_launch(void* const* d_in, const int* in_sizes, int n_in,
                              void* d_out, int out_size, void* d_ws, size_t ws_size,
                              hipStream_t stream) {
    const float* q = (const float*)d_in[0];
    const float* g = (const float*)d_in[1];
    char* ws = (char*)d_ws;
    char*  qb     = ws;                                        // 2 MiB fp8 panels
    char*  gb     = ws + (2u << 20);                           // 2 MiB fp8 panels
    float* diag   = (float*)(ws + (4u << 20));                 // 32 KiB
    float* zpart  = (float*)(ws + (4u << 20) + (32u << 10));   // 1 MiB
    float* partial= (float*)(ws + (4u << 20) + (1056u << 10)); // 128 B
    k_cvt <<<2048, 256, 0, stream>>>(q, g, qb, gb);
    k_main<<<1024, 256, 0, stream>>>(qb, gb, zpart, diag);
    k_fin1<<<32,   256, 0, stream>>>(zpart, diag, partial);
    k_fin2<<<1,     64, 0, stream>>>(partial, (float*)d_out);
    (void)in_sizes; (void)n_in; (void)out_size; (void)ws_size;
}

// Round 2
// 96.169 us; speedup vs baseline: 2.7888x; 2.7888x over previous
//
#include <hip/hip_runtime.h>
#include <stdint.h>

// triplet_loss_cl: loss = mean_i(-log(softmax(q G^T)[i,i] + 1e-5)), N=8192, D=256.
// Flash-style, never materialize logits. q pre-scaled by log2(e); MFMA C-input
// initialized to -KOFF so logits exit MFMA already offset; epilogue is bare exp2.
// Offset cancels exactly in p = exp2(l_ii)/sum exp2(l).
//
// Round 8: keep MX-scaled fp8 MFMA (2x non-scaled fp8 rate) but fix the round-7
// scratch spill: arch-VGPR pressure was ~135 > the 128 arch/AGPR split, so A
// fragments spilled every iteration (WRITE_SIZE 320MB, 186us). Restructure to
// 8 waves x 32 rows (512-thread block): afrag 64->32 VGPRs, pressure ~85.
// Grid/LDS/DMA/ds_read/MFMA counts per block are unchanged.
// A/B use the identical chunk packing, so any k-permutation in the HW fragment
// map applies to both operands and cancels in the dot product.

#define LOG2E 1.44269504f
#define KOFF  92.3324826f          // 64 * log2(e); cancels exactly in p = e_ii/Z

typedef __attribute__((ext_vector_type(4))) float f32x4;
typedef __attribute__((ext_vector_type(4))) int   i32x4;
typedef __attribute__((ext_vector_type(8))) int   i32x8;

typedef __attribute__((address_space(1))) const uint32_t gu32;
typedef __attribute__((address_space(3))) uint32_t lu32;

static __device__ __forceinline__ i32x8 cat8(i32x4 lo, i32x4 hi) {
    i32x8 r;
    r[0] = lo[0]; r[1] = lo[1]; r[2] = lo[2]; r[3] = lo[3];
    r[4] = hi[0]; r[5] = hi[1]; r[6] = hi[2]; r[7] = hi[3];
    return r;
}

// ---- kernel 0: fp32 row-major [8192][256] -> fp8 e4m3 K=128 fragment layout ----
// Panel = 64 rows x 256 k = 16 KB, split into 8 tiles (kb in 2, cf in 4) of 2 KB.
// Tile holds rows cf*16+l15, k = kb*128 + quad*32 .. +32 per lane (l=quad*16+l15),
// stored as [h in 2][lane][16B] so fragment loads are linear b128 pairs.
// Thread o -> row = o>>5 (coalesced reads), slot = o&31 (8 k-values each).
__global__ __launch_bounds__(256) void k_cvt(const float* __restrict__ q,
                                             const float* __restrict__ g,
                                             char* __restrict__ qb,
                                             char* __restrict__ gb) {
    int o = blockIdx.x * 256 + threadIdx.x;        // grid 2048: q then g
    const float* src = q;
    char* dst = qb;
    float sc = LOG2E;
    if (o >= 262144) { o -= 262144; src = g; dst = gb; sc = 1.0f; }
    int row = o >> 5, slot = o & 31;
    const float4* sp = (const float4*)(src + row * 256 + slot * 8);
    float4 a = sp[0], b = sp[1];
    uint32_t w0 = __builtin_amdgcn_cvt_pk_fp8_f32(a.x * sc, a.y * sc, 0, false);
    w0 = __builtin_amdgcn_cvt_pk_fp8_f32(a.z * sc, a.w * sc, w0, true);
    uint32_t w1 = __builtin_amdgcn_cvt_pk_fp8_f32(b.x * sc, b.y * sc, 0, false);
    w1 = __builtin_amdgcn_cvt_pk_fp8_f32(b.z * sc, b.w * sc, w1, true);
    int p = row >> 6, cf = (row >> 4) & 3, l15 = row & 15;
    int kb = slot >> 4;                            // which 128-k block
    int gi = slot & 15;                            // 8-byte granule within block
    int quad = gi >> 2;                            // lane quad (k = quad*32..+32)
    int j = gi & 3;                                // byte granule within lane's 32B
    uint2 wv; wv.x = w0; wv.y = w1;
    *(uint2*)(dst + (size_t)p * 16384 + ((kb * 4 + cf) << 11)
              + ((j >> 1) << 10) + (quad * 16 + l15) * 16 + (j & 1) * 8) = wv;
}

// ---- kernel 1: per-row Z partials (+ diagonal offset-logits) ----
// grid 1024 = 32 row-tiles (BM=256) x 32 col-splits (256 cols). 8 waves x 32 rows.
// Per jt (64-col tile): DMA 16 KB to LDS, 4 cf x (4 ds_read_b128 + 4 MX-MFMA),
// exp2 epilogue. Unit scales (e8m0 0x7F = 2^0) keep the math exact fp8.
__global__ __launch_bounds__(512, 2) void k_main(const char* __restrict__ qb,
                                                 const char* __restrict__ gb,
                                                 float* __restrict__ zpart,
                                                 float* __restrict__ diag) {
    __shared__ char lds[16384];                    // one 64-col fp8 B tile
    const int tid  = threadIdx.x;
    const int wave = tid >> 6;                     // 0..7
    const int lane = tid & 63;
    const int l15  = lane & 15;
    const int quad = lane >> 4;
    const int h2   = wave & 1;                     // which 32-row half of panel
    const int t    = blockIdx.x >> 5;              // row-tile (256 rows)
    const int cs   = blockIdx.x & 31;              // col-split (256 cols)
    const int rowbase = t * 256 + wave * 32;

    // A fragments: wave owns half of q-panel (t*4 + wave/2); tiles cf = h2*2+rg.
    i32x8 afrag[2][2];                             // 32 VGPRs
    {
        const char* qp = qb + (size_t)(t * 4 + (wave >> 1)) * 16384 + lane * 16;
#pragma unroll
        for (int rg = 0; rg < 2; ++rg)
#pragma unroll
            for (int kb = 0; kb < 2; ++kb) {
                const char* tp = qp + ((kb * 4 + h2 * 2 + rg) << 11);
                afrag[rg][kb] = cat8(*(const i32x4*)tp, *(const i32x4*)(tp + 1024));
            }
    }

    float zacc[2][4];
#pragma unroll
    for (int rg = 0; rg < 2; ++rg)
#pragma unroll
        for (int r = 0; r < 4; ++r) zacc[rg][r] = 0.f;

    const bool bd = (t == cs);                     // square block on the diagonal

    for (int jt = 0; jt < 4; ++jt) {
        const char* gp = gb + (size_t)(cs * 4 + jt) * 16384;
        // stage 16 KB: 8 waves x 2 x 1KB DMA (linear; dest = uniform + lane*16)
#pragma unroll
        for (int i = 0; i < 2; ++i) {
            int c = wave * 2 + i;
            __builtin_amdgcn_global_load_lds(
                (gu32*)(gp + (c << 10) + (lane << 4)),
                (lu32*)(lds + (c << 10)), 16, 0, 0);
        }
        __syncthreads();

        const bool dg = bd && (jt == (wave >> 1)); // this tile holds our diagonal
#pragma unroll
        for (int cf = 0; cf < 4; ++cf) {
            f32x4 acc[2];
#pragma unroll
            for (int rg = 0; rg < 2; ++rg)
                acc[rg] = (f32x4){-KOFF, -KOFF, -KOFF, -KOFF};
#pragma unroll
            for (int kb = 0; kb < 2; ++kb) {
                const char* bp = lds + ((kb * 4 + cf) << 11) + lane * 16;
                i32x8 b = cat8(*(const i32x4*)bp, *(const i32x4*)(bp + 1024));
#pragma unroll
                for (int rg = 0; rg < 2; ++rg)
                    acc[rg] = __builtin_amdgcn_mfma_scale_f32_16x16x128_f8f6f4(
                        afrag[rg][kb], b, acc[rg],
                        0, 0,                       // cbsz/blgp: fp8 e4m3 / fp8 e4m3
                        0, 0x7f7f7f7f,              // scale A: e8m0 127 -> x1
                        0, 0x7f7f7f7f);             // scale B: e8m0 127 -> x1
            }
            // C/D layout: col=lane&15, row=quad*4+reg (shape-determined, m127/m128)
#pragma unroll
            for (int rg = 0; rg < 2; ++rg)
#pragma unroll
                for (int r = 0; r < 4; ++r)
                    zacc[rg][r] += __builtin_amdgcn_exp2f(acc[rg][r]);
            if (dg) {                              // diag: cf == h2*2+rg, l15 == quad*4+r
                int rgd = cf - h2 * 2;
                if (rgd >= 0 && rgd < 2) {
#pragma unroll
                    for (int r = 0; r < 4; ++r)
                        if (quad * 4 + r == l15)
                            diag[rowbase + rgd * 16 + l15] = acc[rgd][r];
                }
            }
        }
        __syncthreads();
    }

    // fold the 16 column-lane-classes (lanes differing in bits 0..3 share a row)
#pragma unroll
    for (int d = 1; d < 16; d <<= 1)
#pragma unroll
        for (int rg = 0; rg < 2; ++rg)
#pragma unroll
            for (int r = 0; r < 4; ++r)
                zacc[rg][r] += __shfl_xor(zacc[rg][r], d, 64);

    if (l15 == 0) {
#pragma unroll
        for (int rg = 0; rg < 2; ++rg)
#pragma unroll
            for (int r = 0; r < 4; ++r)
                zpart[(rowbase + rg * 16 + quad * 4 + r) * 32 + cs] = zacc[rg][r];
    }
}

// ---- kernel 2a: per-row loss, 32-block tree ----
__global__ __launch_bounds__(256) void k_fin1(const float* __restrict__ zpart,
                                              const float* __restrict__ diag,
                                              float* __restrict__ partial) {
    __shared__ float red[4];
    int r = blockIdx.x * 256 + threadIdx.x;
    const float4* z = (const float4*)(zpart + r * 32);
    float Z = 0.f;
#pragma unroll
    for (int i = 0; i < 8; ++i) {
        float4 a = z[i];
        Z += (a.x + a.y) + (a.z + a.w);
    }
    float p = __builtin_amdgcn_exp2f(diag[r]) / Z;  // diag already has -KOFF folded
    float v = -logf(p + 1e-5f);
#pragma unroll
    for (int dd = 1; dd < 64; dd <<= 1) v += __shfl_xor(v, dd, 64);
    if ((threadIdx.x & 63) == 0) red[threadIdx.x >> 6] = v;
    __syncthreads();
    if (threadIdx.x == 0)
        partial[blockIdx.x] = (red[0] + red[1]) + (red[2] + red[3]);
}

// ---- kernel 2b: final reduce ----
__global__ void k_fin2(const float* __restrict__ partial, float* __restrict__ out) {
    float v = (threadIdx.x < 32) ? partial[threadIdx.x] : 0.f;
#pragma unroll
    for (int d = 1; d < 32; d <<= 1) v += __shfl_xor(v, d, 64);
    if (threadIdx.x == 0) out[0] = v * (1.f / 8192.f);
}

extern "C" void kernel_launch(void* const* d_in, const int* in_sizes, int n_in,
                              void* d_out, int out_size, void* d_ws, size_t ws_size,
                              hipStream_t stream) {
    const float* q = (const float*)d_in[0];
    const float* g = (const float*)d_in[1];
    char* ws = (char*)d_ws;
    char*  qb     = ws;                                        // 2 MiB fp8 panels
    char*  gb     = ws + (2u << 20);                           // 2 MiB fp8 panels
    float* diag   = (float*)(ws + (4u << 20));                 // 32 KiB
    float* zpart  = (float*)(ws + (4u << 20) + (32u << 10));   // 1 MiB
    float* partial= (float*)(ws + (4u << 20) + (1056u << 10)); // 128 B
    k_cvt <<<2048, 256, 0, stream>>>(q, g, qb, gb);
    k_main<<<1024, 512, 0, stream>>>(qb, gb, zpart, diag);
    k_fin1<<<32,   256, 0, stream>>>(zpart, diag, partial);
    k_fin2<<<1,     64, 0, stream>>>(partial, (float*)d_out);
    (void)in_sizes; (void)n_in; (void)out_size; (void)ws_size;
}

// Round 3
// 93.576 us; speedup vs baseline: 2.8661x; 1.0277x over previous
//
#include <hip/hip_runtime.h>
#include <stdint.h>

// triplet_loss_cl: loss = mean_i(-log(softmax(q G^T)[i,i] + 1e-5)), N=8192, D=256.
// Flash-style, never materialize logits. q pre-scaled by log2(e); MFMA C-input
// initialized to -KOFF so logits exit MFMA already offset; epilogue is bare exp2.
// Offset cancels exactly in p = exp2(l_ii)/sum exp2(l).
//
// Round 9: k_main was ~2x above its MX-MFMA floor (inferred 14.8 vs 7.4 us) --
// single-buffered LDS serialized the 16KB DMA + 2 barriers per jt. Now double-
// buffered (T3-minimum 2-phase): stage jt+1 at top, compute jt, ONE barrier/jt
// whose implicit vmcnt(0) drain is covered by ~1.8us of MFMA work. Also fused
// k_fin2 into k_fin1 (atomic-counter last-block reduce) to drop one launch gap.
// 8 waves x 32 rows (512-thread block) keeps arch-VGPR pressure ~85 < 128.
// A/B use the identical chunk packing, so any k-permutation in the HW fragment
// map applies to both operands and cancels in the dot product.

#define LOG2E 1.44269504f
#define KOFF  92.3324826f          // 64 * log2(e); cancels exactly in p = e_ii/Z

typedef __attribute__((ext_vector_type(4))) float f32x4;
typedef __attribute__((ext_vector_type(4))) int   i32x4;
typedef __attribute__((ext_vector_type(8))) int   i32x8;

typedef __attribute__((address_space(1))) const uint32_t gu32;
typedef __attribute__((address_space(3))) uint32_t lu32;

static __device__ __forceinline__ i32x8 cat8(i32x4 lo, i32x4 hi) {
    i32x8 r;
    r[0] = lo[0]; r[1] = lo[1]; r[2] = lo[2]; r[3] = lo[3];
    r[4] = hi[0]; r[5] = hi[1]; r[6] = hi[2]; r[7] = hi[3];
    return r;
}

// ---- kernel 0: fp32 row-major [8192][256] -> fp8 e4m3 K=128 fragment layout ----
// Panel = 64 rows x 256 k = 16 KB, split into 8 tiles (kb in 2, cf in 4) of 2 KB.
// Tile holds rows cf*16+l15, k = kb*128 + quad*32 .. +32 per lane (l=quad*16+l15),
// stored as [h in 2][lane][16B] so fragment loads are linear b128 pairs.
// Thread o -> row = o>>5 (coalesced reads), slot = o&31 (8 k-values each).
// Also zeroes the fin completion counter (stream-ordered before k_fin).
__global__ __launch_bounds__(256) void k_cvt(const float* __restrict__ q,
                                             const float* __restrict__ g,
                                             char* __restrict__ qb,
                                             char* __restrict__ gb,
                                             unsigned* __restrict__ counter) {
    if (blockIdx.x == 0 && threadIdx.x == 0) *counter = 0u;
    int o = blockIdx.x * 256 + threadIdx.x;        // grid 2048: q then g
    const float* src = q;
    char* dst = qb;
    float sc = LOG2E;
    if (o >= 262144) { o -= 262144; src = g; dst = gb; sc = 1.0f; }
    int row = o >> 5, slot = o & 31;
    const float4* sp = (const float4*)(src + row * 256 + slot * 8);
    float4 a = sp[0], b = sp[1];
    uint32_t w0 = __builtin_amdgcn_cvt_pk_fp8_f32(a.x * sc, a.y * sc, 0, false);
    w0 = __builtin_amdgcn_cvt_pk_fp8_f32(a.z * sc, a.w * sc, w0, true);
    uint32_t w1 = __builtin_amdgcn_cvt_pk_fp8_f32(b.x * sc, b.y * sc, 0, false);
    w1 = __builtin_amdgcn_cvt_pk_fp8_f32(b.z * sc, b.w * sc, w1, true);
    int p = row >> 6, cf = (row >> 4) & 3, l15 = row & 15;
    int kb = slot >> 4;                            // which 128-k block
    int gi = slot & 15;                            // 8-byte granule within block
    int quad = gi >> 2;                            // lane quad (k = quad*32..+32)
    int j = gi & 3;                                // byte granule within lane's 32B
    uint2 wv; wv.x = w0; wv.y = w1;
    *(uint2*)(dst + (size_t)p * 16384 + ((kb * 4 + cf) << 11)
              + ((j >> 1) << 10) + (quad * 16 + l15) * 16 + (j & 1) * 8) = wv;
}

// ---- kernel 1: per-row Z partials (+ diagonal offset-logits) ----
// grid 1024 = 32 row-tiles (BM=256) x 32 col-splits (256 cols). 8 waves x 32 rows.
// Double-buffered B tiles: per jt {stage jt+1 -> buf^1 | 4 cf x (4 ds_read_b128 +
// 4 MX-MFMA) on buf | one barrier}. Unit e8m0 scales (0x7F = 2^0) = exact fp8.
__global__ __launch_bounds__(512, 2) void k_main(const char* __restrict__ qb,
                                                 const char* __restrict__ gb,
                                                 float* __restrict__ zpart,
                                                 float* __restrict__ diag) {
    __shared__ char lds[2][16384];                 // double-buffered 64-col B tile
    const int tid  = threadIdx.x;
    const int wave = tid >> 6;                     // 0..7
    const int lane = tid & 63;
    const int l15  = lane & 15;
    const int quad = lane >> 4;
    const int h2   = wave & 1;                     // which 32-row half of panel
    const int t    = blockIdx.x >> 5;              // row-tile (256 rows)
    const int cs   = blockIdx.x & 31;              // col-split (256 cols)
    const int rowbase = t * 256 + wave * 32;

    // A fragments: wave owns half of q-panel (t*4 + wave/2); tiles cf = h2*2+rg.
    i32x8 afrag[2][2];                             // 32 VGPRs
    {
        const char* qp = qb + (size_t)(t * 4 + (wave >> 1)) * 16384 + lane * 16;
#pragma unroll
        for (int rg = 0; rg < 2; ++rg)
#pragma unroll
            for (int kb = 0; kb < 2; ++kb) {
                const char* tp = qp + ((kb * 4 + h2 * 2 + rg) << 11);
                afrag[rg][kb] = cat8(*(const i32x4*)tp, *(const i32x4*)(tp + 1024));
            }
    }

    float zacc[2][4];
#pragma unroll
    for (int rg = 0; rg < 2; ++rg)
#pragma unroll
        for (int r = 0; r < 4; ++r) zacc[rg][r] = 0.f;

    const bool bd = (t == cs);                     // square block on the diagonal

    // stage(jt, buf): 16 KB DMA, 8 waves x 2 x 1KB (linear; dest = uniform+lane*16)
    const char* gbase = gb + (size_t)(cs * 4) * 16384;
#define STAGE(JT, BUF)                                                        \
    {                                                                         \
        const char* gp = gbase + (size_t)(JT) * 16384;                        \
        _Pragma("unroll")                                                     \
        for (int i = 0; i < 2; ++i) {                                         \
            int c = wave * 2 + i;                                             \
            __builtin_amdgcn_global_load_lds(                                 \
                (gu32*)(gp + (c << 10) + (lane << 4)),                        \
                (lu32*)(&lds[BUF][0] + (c << 10)), 16, 0, 0);                 \
        }                                                                     \
    }

    STAGE(0, 0);
    __syncthreads();                               // implicit vmcnt(0) drain
    int cur = 0;

    for (int jt = 0; jt < 4; ++jt) {
        if (jt < 3) STAGE(jt + 1, cur ^ 1);        // prefetch next tile

        const bool dg = bd && (jt == (wave >> 1)); // this tile holds our diagonal
        const char* lbase = &lds[cur][0];
#pragma unroll
        for (int cf = 0; cf < 4; ++cf) {
            f32x4 acc[2];
#pragma unroll
            for (int rg = 0; rg < 2; ++rg)
                acc[rg] = (f32x4){-KOFF, -KOFF, -KOFF, -KOFF};
#pragma unroll
            for (int kb = 0; kb < 2; ++kb) {
                const char* bp = lbase + ((kb * 4 + cf) << 11) + lane * 16;
                i32x8 b = cat8(*(const i32x4*)bp, *(const i32x4*)(bp + 1024));
#pragma unroll
                for (int rg = 0; rg < 2; ++rg)
                    acc[rg] = __builtin_amdgcn_mfma_scale_f32_16x16x128_f8f6f4(
                        afrag[rg][kb], b, acc[rg],
                        0, 0,                       // cbsz/blgp: fp8 e4m3 / fp8 e4m3
                        0, 0x7f7f7f7f,              // scale A: e8m0 127 -> x1
                        0, 0x7f7f7f7f);             // scale B: e8m0 127 -> x1
            }
            // C/D layout: col=lane&15, row=quad*4+reg (shape-determined, m127/m128)
#pragma unroll
            for (int rg = 0; rg < 2; ++rg)
#pragma unroll
                for (int r = 0; r < 4; ++r)
                    zacc[rg][r] += __builtin_amdgcn_exp2f(acc[rg][r]);
            if (dg) {                              // diag: cf == h2*2+rg, l15 == quad*4+r
                int rgd = cf - h2 * 2;
                if (rgd >= 0 && rgd < 2) {
#pragma unroll
                    for (int r = 0; r < 4; ++r)
                        if (quad * 4 + r == l15)
                            diag[rowbase + rgd * 16 + l15] = acc[rgd][r];
                }
            }
        }
        if (jt < 3) {
            __syncthreads();                       // drains this iter's STAGE (hidden)
            cur ^= 1;
        }
    }
#undef STAGE

    // fold the 16 column-lane-classes (lanes differing in bits 0..3 share a row)
#pragma unroll
    for (int d = 1; d < 16; d <<= 1)
#pragma unroll
        for (int rg = 0; rg < 2; ++rg)
#pragma unroll
            for (int r = 0; r < 4; ++r)
                zacc[rg][r] += __shfl_xor(zacc[rg][r], d, 64);

    if (l15 == 0) {
#pragma unroll
        for (int rg = 0; rg < 2; ++rg)
#pragma unroll
            for (int r = 0; r < 4; ++r)
                zpart[(rowbase + rg * 16 + quad * 4 + r) * 32 + cs] = zacc[rg][r];
    }
}

// ---- kernel 2: per-row loss, 32-block tree + fused last-block final reduce ----
__global__ __launch_bounds__(256) void k_fin(const float* __restrict__ zpart,
                                             const float* __restrict__ diag,
                                             float* __restrict__ partial,
                                             unsigned* __restrict__ counter,
                                             float* __restrict__ out) {
    __shared__ float red[4];
    __shared__ int lastflag;
    int r = blockIdx.x * 256 + threadIdx.x;
    const float4* z = (const float4*)(zpart + r * 32);
    float Z = 0.f;
#pragma unroll
    for (int i = 0; i < 8; ++i) {
        float4 a = z[i];
        Z += (a.x + a.y) + (a.z + a.w);
    }
    float p = __builtin_amdgcn_exp2f(diag[r]) / Z;  // diag already has -KOFF folded
    float v = -logf(p + 1e-5f);
#pragma unroll
    for (int dd = 1; dd < 64; dd <<= 1) v += __shfl_xor(v, dd, 64);
    if ((threadIdx.x & 63) == 0) red[threadIdx.x >> 6] = v;
    __syncthreads();
    if (threadIdx.x == 0) {
        float bsum = (red[0] + red[1]) + (red[2] + red[3]);
        __hip_atomic_store(&partial[blockIdx.x], bsum,
                           __ATOMIC_RELAXED, __HIP_MEMORY_SCOPE_AGENT);
        __threadfence();                           // release our partial
        lastflag = (atomicAdd(counter, 1u) == 31u);
    }
    __syncthreads();
    if (lastflag) {                                // we are the last block
        __threadfence();                           // acquire others' partials
        float v2 = 0.f;
        if (threadIdx.x < 32)
            v2 = __hip_atomic_load(&partial[threadIdx.x],
                                   __ATOMIC_RELAXED, __HIP_MEMORY_SCOPE_AGENT);
        if (threadIdx.x < 64) {
#pragma unroll
            for (int d = 1; d < 32; d <<= 1) v2 += __shfl_xor(v2, d, 64);
            if (threadIdx.x == 0) out[0] = v2 * (1.f / 8192.f);
        }
    }
}

extern "C" void kernel_launch(void* const* d_in, const int* in_sizes, int n_in,
                              void* d_out, int out_size, void* d_ws, size_t ws_size,
                              hipStream_t stream) {
    const float* q = (const float*)d_in[0];
    const float* g = (const float*)d_in[1];
    char* ws = (char*)d_ws;
    char*  qb     = ws;                                        // 2 MiB fp8 panels
    char*  gb     = ws + (2u << 20);                           // 2 MiB fp8 panels
    float* diag   = (float*)(ws + (4u << 20));                 // 32 KiB
    float* zpart  = (float*)(ws + (4u << 20) + (32u << 10));   // 1 MiB
    float* partial= (float*)(ws + (4u << 20) + (1056u << 10)); // 128 B
    unsigned* ctr = (unsigned*)(ws + (4u << 20) + (1056u << 10) + 128);
    k_cvt <<<2048, 256, 0, stream>>>(q, g, qb, gb, ctr);
    k_main<<<1024, 512, 0, stream>>>(qb, gb, zpart, diag);
    k_fin <<<32,   256, 0, stream>>>(zpart, diag, partial, ctr, (float*)d_out);
    (void)in_sizes; (void)n_in; (void)out_size; (void)ws_size;
}

// Round 4
// 93.435 us; speedup vs baseline: 2.8704x; 1.0015x over previous
//
#include <hip/hip_runtime.h>
#include <stdint.h>

// triplet_loss_cl: loss = mean_i(-log(softmax(q G^T)[i,i] + 1e-5)), N=8192, D=256.
// Flash-style, never materialize logits. q pre-scaled by log2(e); MFMA C-input
// initialized to -KOFF so logits exit MFMA already offset; epilogue is bare exp2.
// Offset cancels exactly in p = exp2(l_ii)/sum exp2(l).
//
// Round 10: k_main was LDS-READ-bound: every wave reads the whole 16KB B tile,
// so LDS traffic = totalRows/rowsPerWave * panel = 512MB (~10.2us) > MFMA 7.4us.
// Now 8 waves x 64 rows (BM=512, grid 512): each B fragment feeds 4 MFMAs ->
// 256MB LDS (~4.9us) -> MFMA-bound. Spill guards vs round-7: launch_bounds(512,2)
// (2 waves/SIMD -> 256-reg budget), cf loop NOT unrolled (<=2 B operands in
// flight), kb/rg static (no runtime-indexed arrays -> no scratch).
// A/B use the identical chunk packing, so any k-permutation in the HW fragment
// map applies to both operands and cancels in the dot product.

#define LOG2E 1.44269504f
#define KOFF  92.3324826f          // 64 * log2(e); cancels exactly in p = e_ii/Z

typedef __attribute__((ext_vector_type(4))) float f32x4;
typedef __attribute__((ext_vector_type(4))) int   i32x4;
typedef __attribute__((ext_vector_type(8))) int   i32x8;

typedef __attribute__((address_space(1))) const uint32_t gu32;
typedef __attribute__((address_space(3))) uint32_t lu32;

static __device__ __forceinline__ i32x8 cat8(i32x4 lo, i32x4 hi) {
    i32x8 r;
    r[0] = lo[0]; r[1] = lo[1]; r[2] = lo[2]; r[3] = lo[3];
    r[4] = hi[0]; r[5] = hi[1]; r[6] = hi[2]; r[7] = hi[3];
    return r;
}

// ---- kernel 0: fp32 row-major [8192][256] -> fp8 e4m3 K=128 fragment layout ----
// Panel = 64 rows x 256 k = 16 KB, split into 8 tiles (kb in 2, cf in 4) of 2 KB.
// Tile holds rows cf*16+l15, k = kb*128 + quad*32 .. +32 per lane (l=quad*16+l15),
// stored as [h in 2][lane][16B] so fragment loads are linear b128 pairs.
// Thread o -> row = o>>5 (coalesced reads), slot = o&31 (8 k-values each).
// Also zeroes the fin completion counter (stream-ordered before k_fin).
__global__ __launch_bounds__(256) void k_cvt(const float* __restrict__ q,
                                             const float* __restrict__ g,
                                             char* __restrict__ qb,
                                             char* __restrict__ gb,
                                             unsigned* __restrict__ counter) {
    if (blockIdx.x == 0 && threadIdx.x == 0) *counter = 0u;
    int o = blockIdx.x * 256 + threadIdx.x;        // grid 2048: q then g
    const float* src = q;
    char* dst = qb;
    float sc = LOG2E;
    if (o >= 262144) { o -= 262144; src = g; dst = gb; sc = 1.0f; }
    int row = o >> 5, slot = o & 31;
    const float4* sp = (const float4*)(src + row * 256 + slot * 8);
    float4 a = sp[0], b = sp[1];
    uint32_t w0 = __builtin_amdgcn_cvt_pk_fp8_f32(a.x * sc, a.y * sc, 0, false);
    w0 = __builtin_amdgcn_cvt_pk_fp8_f32(a.z * sc, a.w * sc, w0, true);
    uint32_t w1 = __builtin_amdgcn_cvt_pk_fp8_f32(b.x * sc, b.y * sc, 0, false);
    w1 = __builtin_amdgcn_cvt_pk_fp8_f32(b.z * sc, b.w * sc, w1, true);
    int p = row >> 6, cf = (row >> 4) & 3, l15 = row & 15;
    int kb = slot >> 4;                            // which 128-k block
    int gi = slot & 15;                            // 8-byte granule within block
    int quad = gi >> 2;                            // lane quad (k = quad*32..+32)
    int j = gi & 3;                                // byte granule within lane's 32B
    uint2 wv; wv.x = w0; wv.y = w1;
    *(uint2*)(dst + (size_t)p * 16384 + ((kb * 4 + cf) << 11)
              + ((j >> 1) << 10) + (quad * 16 + l15) * 16 + (j & 1) * 8) = wv;
}

// ---- kernel 1: per-row Z partials (+ diagonal offset-logits) ----
// grid 512 = 16 row-tiles (BM=512) x 32 col-splits (256 cols). 8 waves x 64 rows.
// Double-buffered B tiles: per jt {stage jt+1 -> buf^1 | 4 cf x (4 ds_read_b128 +
// 16 MX-MFMA) on buf | one barrier}. Unit e8m0 scales (0x7F = 2^0) = exact fp8.
__global__ __launch_bounds__(512, 2) void k_main(const char* __restrict__ qb,
                                                 const char* __restrict__ gb,
                                                 float* __restrict__ zpart,
                                                 float* __restrict__ diag) {
    __shared__ char lds[2][16384];                 // double-buffered 64-col B tile
    const int tid  = threadIdx.x;
    const int wave = tid >> 6;                     // 0..7
    const int lane = tid & 63;
    const int l15  = lane & 15;
    const int quad = lane >> 4;
    const int t    = blockIdx.x >> 5;              // row-tile (512 rows), 0..15
    const int cs   = blockIdx.x & 31;              // col-split (256 cols)
    const int p64  = t * 8 + wave;                 // global 64-row panel index
    const int rowbase = p64 * 64;

    // A fragments: wave owns q-panel p64; rowgroup rg = tile cf. 64 VGPRs.
    i32x8 afrag[4][2];
    {
        const char* qp = qb + (size_t)p64 * 16384 + lane * 16;
#pragma unroll
        for (int rg = 0; rg < 4; ++rg)
#pragma unroll
            for (int kb = 0; kb < 2; ++kb) {
                const char* tp = qp + ((kb * 4 + rg) << 11);
                afrag[rg][kb] = cat8(*(const i32x4*)tp, *(const i32x4*)(tp + 1024));
            }
    }

    float zacc[4][4];
#pragma unroll
    for (int rg = 0; rg < 4; ++rg)
#pragma unroll
        for (int r = 0; r < 4; ++r) zacc[rg][r] = 0.f;

    // stage(jt, buf): 16 KB DMA, 8 waves x 2 x 1KB (linear; dest = uniform+lane*16)
    const char* gbase = gb + (size_t)(cs * 4) * 16384;
#define STAGE(JT, BUF)                                                        \
    {                                                                         \
        const char* gp = gbase + (size_t)(JT) * 16384;                        \
        _Pragma("unroll")                                                     \
        for (int i = 0; i < 2; ++i) {                                         \
            int c = wave * 2 + i;                                             \
            __builtin_amdgcn_global_load_lds(                                 \
                (gu32*)(gp + (c << 10) + (lane << 4)),                        \
                (lu32*)(&lds[BUF][0] + (c << 10)), 16, 0, 0);                 \
        }                                                                     \
    }

    STAGE(0, 0);
    __syncthreads();                               // implicit vmcnt(0) drain
    int cur = 0;

    for (int jt = 0; jt < 4; ++jt) {
        if (jt < 3) STAGE(jt + 1, cur ^ 1);        // prefetch next tile

        const bool dg = (cs * 4 + jt == p64);      // tile holds our diagonal
        const char* lbase = &lds[cur][0] + lane * 16;
#pragma unroll 1                                   // runtime cf: caps B in flight
        for (int cf = 0; cf < 4; ++cf) {
            f32x4 acc[4];
#pragma unroll
            for (int rg = 0; rg < 4; ++rg)
                acc[rg] = (f32x4){-KOFF, -KOFF, -KOFF, -KOFF};
#pragma unroll
            for (int kb = 0; kb < 2; ++kb) {
                const char* bp = lbase + (cf << 11) + (kb << 13);
                i32x8 b = cat8(*(const i32x4*)bp, *(const i32x4*)(bp + 1024));
#pragma unroll
                for (int rg = 0; rg < 4; ++rg)
                    acc[rg] = __builtin_amdgcn_mfma_scale_f32_16x16x128_f8f6f4(
                        afrag[rg][kb], b, acc[rg],
                        0, 0,                       // cbsz/blgp: fp8 e4m3 / fp8 e4m3
                        0, 0x7f7f7f7f,              // scale A: e8m0 127 -> x1
                        0, 0x7f7f7f7f);             // scale B: e8m0 127 -> x1
            }
            // C/D layout: col=lane&15, row=quad*4+reg (shape-determined, m127/m128)
#pragma unroll
            for (int rg = 0; rg < 4; ++rg)
#pragma unroll
                for (int r = 0; r < 4; ++r)
                    zacc[rg][r] += __builtin_amdgcn_exp2f(acc[rg][r]);
            if (dg) {                              // diag: rg==cf, l15 == quad*4+r
#pragma unroll
                for (int rg = 0; rg < 4; ++rg)
                    if (rg == cf) {
#pragma unroll
                        for (int r = 0; r < 4; ++r)
                            if (quad * 4 + r == l15)
                                diag[rowbase + cf * 16 + l15] = acc[rg][r];
                    }
            }
        }
        if (jt < 3) {
            __syncthreads();                       // drains this iter's STAGE (hidden)
            cur ^= 1;
        }
    }
#undef STAGE

    // fold the 16 column-lane-classes (lanes differing in bits 0..3 share a row)
#pragma unroll
    for (int d = 1; d < 16; d <<= 1)
#pragma unroll
        for (int rg = 0; rg < 4; ++rg)
#pragma unroll
            for (int r = 0; r < 4; ++r)
                zacc[rg][r] += __shfl_xor(zacc[rg][r], d, 64);

    if (l15 == 0) {
#pragma unroll
        for (int rg = 0; rg < 4; ++rg)
#pragma unroll
            for (int r = 0; r < 4; ++r)
                zpart[(rowbase + rg * 16 + quad * 4 + r) * 32 + cs] = zacc[rg][r];
    }
}

// ---- kernel 2: per-row loss, 32-block tree + fused last-block final reduce ----
__global__ __launch_bounds__(256) void k_fin(const float* __restrict__ zpart,
                                             const float* __restrict__ diag,
                                             float* __restrict__ partial,
                                             unsigned* __restrict__ counter,
                                             float* __restrict__ out) {
    __shared__ float red[4];
    __shared__ int lastflag;
    int r = blockIdx.x * 256 + threadIdx.x;
    const float4* z = (const float4*)(zpart + r * 32);
    float Z = 0.f;
#pragma unroll
    for (int i = 0; i < 8; ++i) {
        float4 a = z[i];
        Z += (a.x + a.y) + (a.z + a.w);
    }
    float p = __builtin_amdgcn_exp2f(diag[r]) / Z;  // diag already has -KOFF folded
    float v = -logf(p + 1e-5f);
#pragma unroll
    for (int dd = 1; dd < 64; dd <<= 1) v += __shfl_xor(v, dd, 64);
    if ((threadIdx.x & 63) == 0) red[threadIdx.x >> 6] = v;
    __syncthreads();
    if (threadIdx.x == 0) {
        float bsum = (red[0] + red[1]) + (red[2] + red[3]);
        __hip_atomic_store(&partial[blockIdx.x], bsum,
                           __ATOMIC_RELAXED, __HIP_MEMORY_SCOPE_AGENT);
        __threadfence();                           // release our partial
        lastflag = (atomicAdd(counter, 1u) == 31u);
    }
    __syncthreads();
    if (lastflag) {                                // we are the last block
        __threadfence();                           // acquire others' partials
        float v2 = 0.f;
        if (threadIdx.x < 32)
            v2 = __hip_atomic_load(&partial[threadIdx.x],
                                   __ATOMIC_RELAXED, __HIP_MEMORY_SCOPE_AGENT);
        if (threadIdx.x < 64) {
#pragma unroll
            for (int d = 1; d < 32; d <<= 1) v2 += __shfl_xor(v2, d, 64);
            if (threadIdx.x == 0) out[0] = v2 * (1.f / 8192.f);
        }
    }
}

extern "C" void kernel_launch(void* const* d_in, const int* in_sizes, int n_in,
                              void* d_out, int out_size, void* d_ws, size_t ws_size,
                              hipStream_t stream) {
    const float* q = (const float*)d_in[0];
    const float* g = (const float*)d_in[1];
    char* ws = (char*)d_ws;
    char*  qb     = ws;                                        // 2 MiB fp8 panels
    char*  gb     = ws + (2u << 20);                           // 2 MiB fp8 panels
    float* diag   = (float*)(ws + (4u << 20));                 // 32 KiB
    float* zpart  = (float*)(ws + (4u << 20) + (32u << 10));   // 1 MiB
    float* partial= (float*)(ws + (4u << 20) + (1056u << 10)); // 128 B
    unsigned* ctr = (unsigned*)(ws + (4u << 20) + (1056u << 10) + 128);
    k_cvt <<<2048, 256, 0, stream>>>(q, g, qb, gb, ctr);
    k_main<<<512,  512, 0, stream>>>(qb, gb, zpart, diag);
    k_fin <<<32,   256, 0, stream>>>(zpart, diag, partial, ctr, (float*)d_out);
    (void)in_sizes; (void)n_in; (void)out_size; (void)ws_size;
}